// Round 5
// baseline (280.707 us; speedup 1.0000x reference)
//
#include <hip/hip_runtime.h>
#include <cstdint>

// Problem constants
#define GQ 4
#define KQ 1024
#define DQ 256     // = GQ * dq
#define dq 64
#define NQ 32768   // B*S = 8*4096
#define DECAYF 0.99f
#define EPSF 1e-5f

// Output flat offsets (floats)
#define OFF_ZQ    0
#define OFF_IND   8388608
#define OFF_EMB   8519680
#define OFF_CS    8781824
#define OFF_AVG   8785920

// Workspace layout (bytes)
#define WS_IND   0              // int32 [GQ][NQ]  (transposed ind)
#define WS_E2    524288         // float [GQ][KQ]
#define WS_EH    540672         // ushort(bf16) [GQ][KQ][dq]  embed hi
#define WS_EL    1064960        // ushort(bf16) [GQ][KQ][dq]  embed lo
#define WS_TOT   1589248        // float [GQ]
#define WS_CTR   1589264        // int
#define WS_LIST  1589280        // int2 [CAP]
#define CAP      16384

#define MARGIN 0.02f

#define MBLK 64    // rows per block

typedef __attribute__((ext_vector_type(8))) short bf16x8;
typedef __attribute__((ext_vector_type(4))) float f32x4;

// cheap f32 -> bf16 hi/lo split of 8 values: hi = truncate, lo = RNE(residual)
__device__ __forceinline__ void split8_fast(float4 u, float4 v, bf16x8& h, bf16x8& l) {
    float f[8] = {u.x, u.y, u.z, u.w, v.x, v.y, v.z, v.w};
#pragma unroll
    for (int j = 0; j < 8; ++j) {
        uint32_t b = __float_as_uint(f[j]);
        uint32_t hb = b & 0xffff0000u;
        float r = f[j] - __uint_as_float(hb);
        uint32_t rb = __float_as_uint(r);
        h[j] = (short)(hb >> 16);
        l[j] = (short)((rb + 0x7fffu + ((rb >> 16) & 1u)) >> 16);
    }
}

// ---- prep: e2[g][k] = sum_j embed^2 ; split embed into bf16 hi/lo (RNE hi) ----
__global__ void k_prep(const float* __restrict__ embed, float* __restrict__ e2,
                       ushort* __restrict__ eh, ushort* __restrict__ el) {
    int t = blockIdx.x * blockDim.x + threadIdx.x; // 0..GQ*KQ-1
    const float* row = embed + (size_t)t * dq;
    ushort* hrow = eh + (size_t)t * dq;
    ushort* lrow = el + (size_t)t * dq;
    float s = 0.f;
#pragma unroll 8
    for (int j = 0; j < dq; ++j) {
        float f = row[j];
        s = fmaf(f, f, s);
        uint32_t b = __float_as_uint(f);
        uint32_t hb = (b + 0x7fffu + ((b >> 16) & 1u)) & 0xffff0000u;
        float hf = __uint_as_float(hb);
        float r = f - hf;
        uint32_t rb = __float_as_uint(r);
        hrow[j] = (ushort)(hb >> 16);
        lrow[j] = (ushort)((rb + 0x7fffu + ((rb >> 16) & 1u)) >> 16);
    }
    e2[t] = s;
}

// ---- MFMA scores + fused top-2 argmax ----
// 4 waves as 2x2: wr = row half (32 rows), wc = col half (512 cols)
// Register ping-pong: prefetch next B half-chunk while MFMA'ing current.
#define LOADB(BH, BL, ch, c)                                                    \
    do {                                                                        \
        size_t base_ = (size_t)(wbase + (ch) * 64) * dq + (c) * 32 + l4 * 8;    \
        _Pragma("unroll")                                                       \
        for (int n_ = 0; n_ < 4; ++n_) {                                        \
            size_t off_ = base_ + (size_t)(n_ * 16 + l15) * dq;                 \
            BH[n_] = *reinterpret_cast<const bf16x8*>(ehg + off_);              \
            BL[n_] = *reinterpret_cast<const bf16x8*>(elg + off_);              \
        }                                                                       \
    } while (0)

#define MMHALF(BH, BL, c)                                                       \
    do {                                                                        \
        _Pragma("unroll")                                                       \
        for (int m_ = 0; m_ < 2; ++m_)                                          \
            _Pragma("unroll")                                                   \
            for (int n_ = 0; n_ < 4; ++n_) {                                    \
                acc[m_][n_] = __builtin_amdgcn_mfma_f32_16x16x32_bf16(          \
                    ah[m_][c], BH[n_], acc[m_][n_], 0, 0, 0);                   \
                acc[m_][n_] = __builtin_amdgcn_mfma_f32_16x16x32_bf16(          \
                    ah[m_][c], BL[n_], acc[m_][n_], 0, 0, 0);                   \
                acc[m_][n_] = __builtin_amdgcn_mfma_f32_16x16x32_bf16(          \
                    al[m_][c], BH[n_], acc[m_][n_], 0, 0, 0);                   \
            }                                                                   \
    } while (0)

__launch_bounds__(256, 3)
__global__ void k_scores_mfma(const float* __restrict__ x,
                              const ushort* __restrict__ eh,
                              const ushort* __restrict__ el,
                              const float* __restrict__ e2,
                              int* __restrict__ ind_t,
                              int* __restrict__ ctr, int2* __restrict__ list) {
    int g = blockIdx.y;
    int n0 = blockIdx.x * MBLK;
    int wid = threadIdx.x >> 6;
    int wr = wid >> 1, wc = wid & 1;
    int lane = threadIdx.x & 63;
    int l15 = lane & 15, l4 = lane >> 4;

    __shared__ float cm1[2][MBLK];
    __shared__ float cm2[2][MBLK];
    __shared__ int   ckk[2][MBLK];

    // A fragments: rows n0 + wr*32 + m*16 + l15, k = c*32 + l4*8 + j
    bf16x8 ah[2][2], al[2][2];
#pragma unroll
    for (int m = 0; m < 2; ++m)
#pragma unroll
        for (int c = 0; c < 2; ++c) {
            const float4* p = reinterpret_cast<const float4*>(
                x + (size_t)(n0 + wr * 32 + m * 16 + l15) * DQ + g * dq + c * 32 + l4 * 8);
            split8_fast(p[0], p[1], ah[m][c], al[m][c]);
        }

    const ushort* ehg = eh + (size_t)g * KQ * dq;
    const ushort* elg = el + (size_t)g * KQ * dq;
    const float*  e2g = e2 + (size_t)g * KQ;

    float m1[2][4], m2[2][4];
    int   k1[2][4];
#pragma unroll
    for (int m = 0; m < 2; ++m)
#pragma unroll
        for (int r = 0; r < 4; ++r) { m1[m][r] = -3.4e38f; m2[m][r] = -3.4e38f; k1[m][r] = 0; }

    int wbase = wc * 512;
    bf16x8 bhA[4], blA[4], bhB[4], blB[4];
    LOADB(bhA, blA, 0, 0);    // prologue: chunk 0, even half

#pragma unroll 1
    for (int ch = 0; ch < 8; ++ch) {
        int cb = wbase + ch * 64;
        f32x4 acc[2][4];
#pragma unroll
        for (int m = 0; m < 2; ++m)
#pragma unroll
            for (int n = 0; n < 4; ++n) acc[m][n] = (f32x4){0.f, 0.f, 0.f, 0.f};

        LOADB(bhB, blB, ch, 1);          // issue odd half
        MMHALF(bhA, blA, 0);             // compute even half (waits on A only)
        if (ch < 7) LOADB(bhA, blA, ch + 1, 0);  // issue next chunk's even half
        MMHALF(bhB, blB, 1);             // compute odd half

        // epilogue: s = 2*dot - e2 ; top-2 per (m,r)
#pragma unroll
        for (int n = 0; n < 4; ++n) {
            int col = cb + n * 16 + l15;
            float e2v = e2g[col];
#pragma unroll
            for (int m = 0; m < 2; ++m)
#pragma unroll
                for (int r = 0; r < 4; ++r) {
                    float s = fmaf(2.0f, acc[m][n][r], -e2v);
                    bool gt = s > m1[m][r];
                    m2[m][r] = __builtin_amdgcn_fmed3f(s, m1[m][r], m2[m][r]);
                    k1[m][r] = gt ? col : k1[m][r];
                    m1[m][r] = fmaxf(m1[m][r], s);
                }
        }
    }

    // cross-lane reduce over the 16 col-lanes
#pragma unroll
    for (int m = 0; m < 2; ++m)
#pragma unroll
        for (int r = 0; r < 4; ++r) {
            float a1 = m1[m][r], a2 = m2[m][r];
            int ak = k1[m][r];
#pragma unroll
            for (int d = 1; d < 16; d <<= 1) {
                float o1 = __shfl_xor(a1, d, 64);
                float o2 = __shfl_xor(a2, d, 64);
                int   ok = __shfl_xor(ak, d, 64);
                bool sw = (o1 > a1) || (o1 == a1 && ok < ak);
                float big = sw ? o1 : a1;
                int bigk = sw ? ok : ak;
                float small = sw ? a1 : o1;
                a2 = fmaxf(fmaxf(a2, o2), small);
                a1 = big; ak = bigk;
            }
            if (l15 == 0) {
                int row = wr * 32 + m * 16 + l4 * 4 + r;   // 0..63
                cm1[wc][row] = a1;
                cm2[wc][row] = a2;
                ckk[wc][row] = ak;
            }
        }
    __syncthreads();

    if (threadIdx.x < MBLK) {
        int row = threadIdx.x;
        float a1 = cm1[0][row], a2 = cm2[0][row];
        int ak = ckk[0][row];
        {
            float o1 = cm1[1][row], o2 = cm2[1][row];
            int ok = ckk[1][row];
            bool sw = (o1 > a1) || (o1 == a1 && ok < ak);
            float big = sw ? o1 : a1;
            int bigk = sw ? ok : ak;
            float small = sw ? a1 : o1;
            a2 = fmaxf(fmaxf(a2, o2), small);
            a1 = big; ak = bigk;
        }
        ind_t[(size_t)g * NQ + n0 + row] = ak;
        if (a1 - a2 < MARGIN) {
            int idx = atomicAdd(ctr, 1);
            if (idx < CAP) list[idx] = make_int2(n0 + row, g);
        }
    }
}

// ---- f64 recheck of flagged queries ----
__launch_bounds__(256)
__global__ void k_recheck(const float* __restrict__ x, const float* __restrict__ embed,
                          const int* __restrict__ ctr, const int2* __restrict__ list,
                          int* __restrict__ ind_t) {
    __shared__ double sv[256];
    __shared__ int si[256];
    int nitems = *ctr;
    if (nitems > CAP) nitems = CAP;
    for (int it = blockIdx.x; it < nitems; it += gridDim.x) {
        int2 q = list[it];
        int n = q.x, g = q.y;
        const float* xrow = x + (size_t)n * DQ + g * dq;
        double best = -1e300;
        int bk = KQ;
        for (int k = threadIdx.x; k < KQ; k += 256) {
            const float* er = embed + ((size_t)g * KQ + k) * dq;
            double dot = 0.0, ee = 0.0;
#pragma unroll 8
            for (int j = 0; j < dq; ++j) {
                double ev = (double)er[j];
                dot = fma((double)xrow[j], ev, dot);
                ee = fma(ev, ev, ee);
            }
            double s = 2.0 * dot - ee;
            if (s > best || (s == best && k < bk)) { best = s; bk = k; }
        }
        sv[threadIdx.x] = best; si[threadIdx.x] = bk;
        __syncthreads();
        for (int off = 128; off > 0; off >>= 1) {
            if (threadIdx.x < off) {
                double ov = sv[threadIdx.x + off]; int oi = si[threadIdx.x + off];
                if (ov > sv[threadIdx.x] || (ov == sv[threadIdx.x] && oi < si[threadIdx.x])) {
                    sv[threadIdx.x] = ov; si[threadIdx.x] = oi;
                }
            }
            __syncthreads();
        }
        if (threadIdx.x == 0) ind_t[(size_t)g * NQ + n] = si[0];
        __syncthreads();
    }
}

// ---- zq gather + ind output ----
__global__ void k_gather(const float* __restrict__ embed, const int* __restrict__ ind_t,
                         float* __restrict__ zq, float* __restrict__ ind_out) {
    int t = blockIdx.x * 256 + threadIdx.x;   // float4 index
    int j4 = t & 15;
    int g = (t >> 4) & 3;
    int n = t >> 6;
    int k = ind_t[(size_t)g * NQ + n];
    const float4* e4 = reinterpret_cast<const float4*>(embed) + ((size_t)(g * KQ + k) * 16 + j4);
    reinterpret_cast<float4*>(zq)[t] = *e4;
    if (t < NQ * GQ) {
        int n2 = t >> 2, g2 = t & 3;
        ind_out[t] = (float)ind_t[(size_t)g2 * NQ + n2];
    }
}

// ---- segment sum v2: 8 bins/block, 8 waves split the N-scan, LDS accumulate ----
#define SB 8   // bins per block
#define SW 8   // waves per block
__launch_bounds__(512)
__global__ void k_segsum2(const float* __restrict__ x, const int* __restrict__ ind_t,
                          const float* __restrict__ embed_avg, const float* __restrict__ cs,
                          float* __restrict__ out_cs, float* __restrict__ out_avg) {
    __shared__ float lacc[SW][SB][64];
    __shared__ int   lcnt[SW][SB];

    int g = blockIdx.x >> 7;            // 512 blocks: 4 g * 128
    int kbase = (blockIdx.x & 127) * SB;
    int wid = threadIdx.x >> 6;
    int lane = threadIdx.x & 63;

    for (int i = threadIdx.x; i < SW * SB * 64; i += 512) ((float*)lacc)[i] = 0.f;
    if (threadIdx.x < SW * SB) ((int*)lcnt)[threadIdx.x] = 0;
    __syncthreads();

    const int* ip = ind_t + (size_t)g * NQ;
    const float* xg = x + g * dq;
    int cnt0 = 0, cnt1 = 0, cnt2 = 0, cnt3 = 0, cnt4 = 0, cnt5 = 0, cnt6 = 0, cnt7 = 0;
    int wbase = wid * (NQ / SW);

    for (int n0 = wbase; n0 < wbase + NQ / SW; n0 += 256) {
        int v0 = ip[n0 + lane];
        int v1 = ip[n0 + 64 + lane];
        int v2 = ip[n0 + 128 + lane];
        int v3 = ip[n0 + 192 + lane];
#pragma unroll
        for (int u = 0; u < 4; ++u) {
            int v = u == 0 ? v0 : (u == 1 ? v1 : (u == 2 ? v2 : v3));
            int d = v - kbase;
            cnt0 += __popcll(__ballot(d == 0));
            cnt1 += __popcll(__ballot(d == 1));
            cnt2 += __popcll(__ballot(d == 2));
            cnt3 += __popcll(__ballot(d == 3));
            cnt4 += __popcll(__ballot(d == 4));
            cnt5 += __popcll(__ballot(d == 5));
            cnt6 += __popcll(__ballot(d == 6));
            cnt7 += __popcll(__ballot(d == 7));
            unsigned long long mask = __ballot((unsigned)d < (unsigned)SB);
            while (mask) {
                int i = __ffsll(mask) - 1;
                mask &= mask - 1;
                int b = __shfl(d, i, 64);        // uniform
                int nv = n0 + u * 64 + i;
                lacc[wid][b][lane] += xg[(size_t)nv * DQ + lane];
            }
        }
    }
    if (lane == 0) {
        lcnt[wid][0] = cnt0; lcnt[wid][1] = cnt1; lcnt[wid][2] = cnt2; lcnt[wid][3] = cnt3;
        lcnt[wid][4] = cnt4; lcnt[wid][5] = cnt5; lcnt[wid][6] = cnt6; lcnt[wid][7] = cnt7;
    }
    __syncthreads();

    int b = threadIdx.x >> 6;           // 0..7
    int l = threadIdx.x & 63;
    float a = 0.f;
#pragma unroll
    for (int w = 0; w < SW; ++w) a += lacc[w][b][l];
    int gk = g * KQ + kbase + b;
    float nea = DECAYF * embed_avg[(size_t)gk * dq + l] + (1.0f - DECAYF) * a;
    out_avg[(size_t)gk * dq + l] = nea;
    if (l == 0) {
        int c = 0;
#pragma unroll
        for (int w = 0; w < SW; ++w) c += lcnt[w][b];
        out_cs[gk] = DECAYF * cs[gk] + (1.0f - DECAYF) * (float)c;
    }
}

// ---- tot[g] ----
__global__ void k_tot(const float* __restrict__ out_cs, float* __restrict__ tot) {
    int g = blockIdx.x;
    __shared__ float red[256];
    float s = 0.f;
    for (int k = threadIdx.x; k < KQ; k += 256) s += out_cs[g * KQ + k];
    red[threadIdx.x] = s;
    __syncthreads();
    for (int off = 128; off > 0; off >>= 1) {
        if (threadIdx.x < off) red[threadIdx.x] += red[threadIdx.x + off];
        __syncthreads();
    }
    if (threadIdx.x == 0) tot[g] = red[0];
}

// ---- new_embed ----
__global__ void k_embed(const float* __restrict__ out_avg, const float* __restrict__ out_cs,
                        const float* __restrict__ tot, float* __restrict__ out_embed) {
    int t = blockIdx.x * 256 + threadIdx.x;
    int gk = t >> 6;
    int g = gk >> 10;
    double ncs = (double)out_cs[gk];
    double tt = (double)tot[g];
    double sm = (ncs + (double)EPSF) / (tt + (double)KQ * (double)EPSF) * tt;
    out_embed[t] = (float)((double)out_avg[t] / sm);
}

extern "C" void kernel_launch(void* const* d_in, const int* in_sizes, int n_in,
                              void* d_out, int out_size, void* d_ws, size_t ws_size,
                              hipStream_t stream) {
    const float* x         = (const float*)d_in[0];
    const float* embed     = (const float*)d_in[1];
    const float* embed_avg = (const float*)d_in[2];
    const float* cs        = (const float*)d_in[3];
    float* out = (float*)d_out;
    float* zq        = out + OFF_ZQ;
    float* ind_out   = out + OFF_IND;
    float* out_embed = out + OFF_EMB;
    float* out_cs    = out + OFF_CS;
    float* out_avg   = out + OFF_AVG;

    char* ws = (char*)d_ws;
    int*    ind_t = (int*)(ws + WS_IND);
    float*  e2    = (float*)(ws + WS_E2);
    ushort* eh    = (ushort*)(ws + WS_EH);
    ushort* el    = (ushort*)(ws + WS_EL);
    float*  tot   = (float*)(ws + WS_TOT);
    int*    ctr   = (int*)(ws + WS_CTR);
    int2*   list  = (int2*)(ws + WS_LIST);

    hipMemsetAsync(ctr, 0, sizeof(int), stream);
    k_prep<<<GQ * KQ / 256, 256, 0, stream>>>(embed, e2, eh, el);
    dim3 g1(NQ / MBLK, GQ);
    k_scores_mfma<<<g1, 256, 0, stream>>>(x, eh, el, e2, ind_t, ctr, list);
    k_recheck<<<256, 256, 0, stream>>>(x, embed, ctr, list, ind_t);
    k_gather<<<(NQ * GQ * 16) / 256, 256, 0, stream>>>(embed, ind_t, zq, ind_out);
    k_segsum2<<<512, 512, 0, stream>>>(x, ind_t, embed_avg, cs, out_cs, out_avg);
    k_tot<<<GQ, 256, 0, stream>>>(out_cs, tot);
    k_embed<<<(GQ * KQ * dq) / 256, 256, 0, stream>>>(out_avg, out_cs, tot, out_embed);
}

// Round 6
// 255.468 us; speedup vs baseline: 1.0988x; 1.0988x over previous
//
#include <hip/hip_runtime.h>
#include <cstdint>

// Problem constants
#define GQ 4
#define KQ 1024
#define DQ 256     // = GQ * dq
#define dq 64
#define NQ 32768   // B*S = 8*4096
#define DECAYF 0.99f
#define EPSF 1e-5f

// Output flat offsets (floats)
#define OFF_ZQ    0
#define OFF_IND   8388608
#define OFF_EMB   8519680
#define OFF_CS    8781824
#define OFF_AVG   8785920

// Workspace layout (bytes)
#define WS_IND   0              // int32 [GQ][NQ]  (transposed ind)
#define WS_E2    524288         // float [GQ][KQ]
#define WS_EH    540672         // ushort(bf16) [GQ][KQ][dq]  embed hi
#define WS_EL    1064960        // ushort(bf16) [GQ][KQ][dq]  embed lo
#define WS_TOT   1589248        // float [GQ]
#define WS_CTR   1589264        // int
#define WS_LIST  1589280        // int2 [CAP]
#define CAP      16384

#define MARGIN 0.02f

#define MBLK 64    // rows per block

typedef __attribute__((ext_vector_type(8))) short bf16x8;
typedef __attribute__((ext_vector_type(4))) float f32x4;

// cheap f32 -> bf16 hi/lo split of 8 values: hi = truncate, lo = RNE(residual)
__device__ __forceinline__ void split8_fast(float4 u, float4 v, bf16x8& h, bf16x8& l) {
    float f[8] = {u.x, u.y, u.z, u.w, v.x, v.y, v.z, v.w};
#pragma unroll
    for (int j = 0; j < 8; ++j) {
        uint32_t b = __float_as_uint(f[j]);
        uint32_t hb = b & 0xffff0000u;
        float r = f[j] - __uint_as_float(hb);
        uint32_t rb = __float_as_uint(r);
        h[j] = (short)(hb >> 16);
        l[j] = (short)((rb + 0x7fffu + ((rb >> 16) & 1u)) >> 16);
    }
}

// ---- prep: e2[g][k] = sum_j embed^2 ; split embed into bf16 hi/lo (RNE hi) ----
__global__ void k_prep(const float* __restrict__ embed, float* __restrict__ e2,
                       ushort* __restrict__ eh, ushort* __restrict__ el) {
    int t = blockIdx.x * blockDim.x + threadIdx.x; // 0..GQ*KQ-1
    const float* row = embed + (size_t)t * dq;
    ushort* hrow = eh + (size_t)t * dq;
    ushort* lrow = el + (size_t)t * dq;
    float s = 0.f;
#pragma unroll 8
    for (int j = 0; j < dq; ++j) {
        float f = row[j];
        s = fmaf(f, f, s);
        uint32_t b = __float_as_uint(f);
        uint32_t hb = (b + 0x7fffu + ((b >> 16) & 1u)) & 0xffff0000u;
        float hf = __uint_as_float(hb);
        float r = f - hf;
        uint32_t rb = __float_as_uint(r);
        hrow[j] = (ushort)(hb >> 16);
        lrow[j] = (ushort)((rb + 0x7fffu + ((rb >> 16) & 1u)) >> 16);
    }
    e2[t] = s;
}

// ---- MFMA scores + fused top-2 argmax ----
// 4 waves as 2x2: wr = row half (32 rows), wc = col half (512 cols)
// Register ping-pong: prefetch next B half-chunk while MFMA'ing current.
// launch_bounds(256,2): ~256 VGPR budget so the ping-pong buffers stay in
// registers — (256,3) made the compiler spill them to scratch (R5:
// WRITE_SIZE 0.54->26.5 MB, dur +20us).
#define LOADB(BH, BL, ch, c)                                                    \
    do {                                                                        \
        size_t base_ = (size_t)(wbase + (ch) * 64) * dq + (c) * 32 + l4 * 8;    \
        _Pragma("unroll")                                                       \
        for (int n_ = 0; n_ < 4; ++n_) {                                        \
            size_t off_ = base_ + (size_t)(n_ * 16 + l15) * dq;                 \
            BH[n_] = *reinterpret_cast<const bf16x8*>(ehg + off_);              \
            BL[n_] = *reinterpret_cast<const bf16x8*>(elg + off_);              \
        }                                                                       \
    } while (0)

#define MMHALF(BH, BL, c)                                                       \
    do {                                                                        \
        _Pragma("unroll")                                                       \
        for (int m_ = 0; m_ < 2; ++m_)                                          \
            _Pragma("unroll")                                                   \
            for (int n_ = 0; n_ < 4; ++n_) {                                    \
                acc[m_][n_] = __builtin_amdgcn_mfma_f32_16x16x32_bf16(          \
                    ah[m_][c], BH[n_], acc[m_][n_], 0, 0, 0);                   \
                acc[m_][n_] = __builtin_amdgcn_mfma_f32_16x16x32_bf16(          \
                    ah[m_][c], BL[n_], acc[m_][n_], 0, 0, 0);                   \
                acc[m_][n_] = __builtin_amdgcn_mfma_f32_16x16x32_bf16(          \
                    al[m_][c], BH[n_], acc[m_][n_], 0, 0, 0);                   \
            }                                                                   \
    } while (0)

__launch_bounds__(256, 2)
__global__ void k_scores_mfma(const float* __restrict__ x,
                              const ushort* __restrict__ eh,
                              const ushort* __restrict__ el,
                              const float* __restrict__ e2,
                              int* __restrict__ ind_t,
                              int* __restrict__ ctr, int2* __restrict__ list) {
    int g = blockIdx.y;
    int n0 = blockIdx.x * MBLK;
    int wid = threadIdx.x >> 6;
    int wr = wid >> 1, wc = wid & 1;
    int lane = threadIdx.x & 63;
    int l15 = lane & 15, l4 = lane >> 4;

    __shared__ float cm1[2][MBLK];
    __shared__ float cm2[2][MBLK];
    __shared__ int   ckk[2][MBLK];

    // A fragments: rows n0 + wr*32 + m*16 + l15, k = c*32 + l4*8 + j
    bf16x8 ah[2][2], al[2][2];
#pragma unroll
    for (int m = 0; m < 2; ++m)
#pragma unroll
        for (int c = 0; c < 2; ++c) {
            const float4* p = reinterpret_cast<const float4*>(
                x + (size_t)(n0 + wr * 32 + m * 16 + l15) * DQ + g * dq + c * 32 + l4 * 8);
            split8_fast(p[0], p[1], ah[m][c], al[m][c]);
        }

    const ushort* ehg = eh + (size_t)g * KQ * dq;
    const ushort* elg = el + (size_t)g * KQ * dq;
    const float*  e2g = e2 + (size_t)g * KQ;

    float m1[2][4], m2[2][4];
    int   k1[2][4];
#pragma unroll
    for (int m = 0; m < 2; ++m)
#pragma unroll
        for (int r = 0; r < 4; ++r) { m1[m][r] = -3.4e38f; m2[m][r] = -3.4e38f; k1[m][r] = 0; }

    int wbase = wc * 512;
    bf16x8 bhA[4], blA[4], bhB[4], blB[4];
    LOADB(bhA, blA, 0, 0);    // prologue: chunk 0, even half

#pragma unroll 1
    for (int ch = 0; ch < 8; ++ch) {
        int cb = wbase + ch * 64;
        f32x4 acc[2][4];
#pragma unroll
        for (int m = 0; m < 2; ++m)
#pragma unroll
            for (int n = 0; n < 4; ++n) acc[m][n] = (f32x4){0.f, 0.f, 0.f, 0.f};

        LOADB(bhB, blB, ch, 1);          // issue odd half
        MMHALF(bhA, blA, 0);             // compute even half (waits on A only)
        if (ch < 7) LOADB(bhA, blA, ch + 1, 0);  // issue next chunk's even half
        MMHALF(bhB, blB, 1);             // compute odd half

        // epilogue: s = 2*dot - e2 ; top-2 per (m,r)
#pragma unroll
        for (int n = 0; n < 4; ++n) {
            int col = cb + n * 16 + l15;
            float e2v = e2g[col];
#pragma unroll
            for (int m = 0; m < 2; ++m)
#pragma unroll
                for (int r = 0; r < 4; ++r) {
                    float s = fmaf(2.0f, acc[m][n][r], -e2v);
                    bool gt = s > m1[m][r];
                    m2[m][r] = __builtin_amdgcn_fmed3f(s, m1[m][r], m2[m][r]);
                    k1[m][r] = gt ? col : k1[m][r];
                    m1[m][r] = fmaxf(m1[m][r], s);
                }
        }
    }

    // cross-lane reduce over the 16 col-lanes
#pragma unroll
    for (int m = 0; m < 2; ++m)
#pragma unroll
        for (int r = 0; r < 4; ++r) {
            float a1 = m1[m][r], a2 = m2[m][r];
            int ak = k1[m][r];
#pragma unroll
            for (int d = 1; d < 16; d <<= 1) {
                float o1 = __shfl_xor(a1, d, 64);
                float o2 = __shfl_xor(a2, d, 64);
                int   ok = __shfl_xor(ak, d, 64);
                bool sw = (o1 > a1) || (o1 == a1 && ok < ak);
                float big = sw ? o1 : a1;
                int bigk = sw ? ok : ak;
                float small = sw ? a1 : o1;
                a2 = fmaxf(fmaxf(a2, o2), small);
                a1 = big; ak = bigk;
            }
            if (l15 == 0) {
                int row = wr * 32 + m * 16 + l4 * 4 + r;   // 0..63
                cm1[wc][row] = a1;
                cm2[wc][row] = a2;
                ckk[wc][row] = ak;
            }
        }
    __syncthreads();

    if (threadIdx.x < MBLK) {
        int row = threadIdx.x;
        float a1 = cm1[0][row], a2 = cm2[0][row];
        int ak = ckk[0][row];
        {
            float o1 = cm1[1][row], o2 = cm2[1][row];
            int ok = ckk[1][row];
            bool sw = (o1 > a1) || (o1 == a1 && ok < ak);
            float big = sw ? o1 : a1;
            int bigk = sw ? ok : ak;
            float small = sw ? a1 : o1;
            a2 = fmaxf(fmaxf(a2, o2), small);
            a1 = big; ak = bigk;
        }
        ind_t[(size_t)g * NQ + n0 + row] = ak;
        if (a1 - a2 < MARGIN) {
            int idx = atomicAdd(ctr, 1);
            if (idx < CAP) list[idx] = make_int2(n0 + row, g);
        }
    }
}

// ---- f64 recheck of flagged queries ----
__launch_bounds__(256)
__global__ void k_recheck(const float* __restrict__ x, const float* __restrict__ embed,
                          const int* __restrict__ ctr, const int2* __restrict__ list,
                          int* __restrict__ ind_t) {
    __shared__ double sv[256];
    __shared__ int si[256];
    int nitems = *ctr;
    if (nitems > CAP) nitems = CAP;
    for (int it = blockIdx.x; it < nitems; it += gridDim.x) {
        int2 q = list[it];
        int n = q.x, g = q.y;
        const float* xrow = x + (size_t)n * DQ + g * dq;
        double best = -1e300;
        int bk = KQ;
        for (int k = threadIdx.x; k < KQ; k += 256) {
            const float* er = embed + ((size_t)g * KQ + k) * dq;
            double dot = 0.0, ee = 0.0;
#pragma unroll 8
            for (int j = 0; j < dq; ++j) {
                double ev = (double)er[j];
                dot = fma((double)xrow[j], ev, dot);
                ee = fma(ev, ev, ee);
            }
            double s = 2.0 * dot - ee;
            if (s > best || (s == best && k < bk)) { best = s; bk = k; }
        }
        sv[threadIdx.x] = best; si[threadIdx.x] = bk;
        __syncthreads();
        for (int off = 128; off > 0; off >>= 1) {
            if (threadIdx.x < off) {
                double ov = sv[threadIdx.x + off]; int oi = si[threadIdx.x + off];
                if (ov > sv[threadIdx.x] || (ov == sv[threadIdx.x] && oi < si[threadIdx.x])) {
                    sv[threadIdx.x] = ov; si[threadIdx.x] = oi;
                }
            }
            __syncthreads();
        }
        if (threadIdx.x == 0) ind_t[(size_t)g * NQ + n] = si[0];
        __syncthreads();
    }
}

// ---- zq gather + ind output ----
__global__ void k_gather(const float* __restrict__ embed, const int* __restrict__ ind_t,
                         float* __restrict__ zq, float* __restrict__ ind_out) {
    int t = blockIdx.x * 256 + threadIdx.x;   // float4 index
    int j4 = t & 15;
    int g = (t >> 4) & 3;
    int n = t >> 6;
    int k = ind_t[(size_t)g * NQ + n];
    const float4* e4 = reinterpret_cast<const float4*>(embed) + ((size_t)(g * KQ + k) * 16 + j4);
    reinterpret_cast<float4*>(zq)[t] = *e4;
    if (t < NQ * GQ) {
        int n2 = t >> 2, g2 = t & 3;
        ind_out[t] = (float)ind_t[(size_t)g2 * NQ + n2];
    }
}

// ---- segment sum v2: 8 bins/block, 8 waves split the N-scan, LDS accumulate ----
#define SB 8   // bins per block
#define SW 8   // waves per block
__launch_bounds__(512)
__global__ void k_segsum2(const float* __restrict__ x, const int* __restrict__ ind_t,
                          const float* __restrict__ embed_avg, const float* __restrict__ cs,
                          float* __restrict__ out_cs, float* __restrict__ out_avg) {
    __shared__ float lacc[SW][SB][64];
    __shared__ int   lcnt[SW][SB];

    int g = blockIdx.x >> 7;            // 512 blocks: 4 g * 128
    int kbase = (blockIdx.x & 127) * SB;
    int wid = threadIdx.x >> 6;
    int lane = threadIdx.x & 63;

    for (int i = threadIdx.x; i < SW * SB * 64; i += 512) ((float*)lacc)[i] = 0.f;
    if (threadIdx.x < SW * SB) ((int*)lcnt)[threadIdx.x] = 0;
    __syncthreads();

    const int* ip = ind_t + (size_t)g * NQ;
    const float* xg = x + g * dq;
    int cnt0 = 0, cnt1 = 0, cnt2 = 0, cnt3 = 0, cnt4 = 0, cnt5 = 0, cnt6 = 0, cnt7 = 0;
    int wbase = wid * (NQ / SW);

    for (int n0 = wbase; n0 < wbase + NQ / SW; n0 += 256) {
        int v0 = ip[n0 + lane];
        int v1 = ip[n0 + 64 + lane];
        int v2 = ip[n0 + 128 + lane];
        int v3 = ip[n0 + 192 + lane];
#pragma unroll
        for (int u = 0; u < 4; ++u) {
            int v = u == 0 ? v0 : (u == 1 ? v1 : (u == 2 ? v2 : v3));
            int d = v - kbase;
            cnt0 += __popcll(__ballot(d == 0));
            cnt1 += __popcll(__ballot(d == 1));
            cnt2 += __popcll(__ballot(d == 2));
            cnt3 += __popcll(__ballot(d == 3));
            cnt4 += __popcll(__ballot(d == 4));
            cnt5 += __popcll(__ballot(d == 5));
            cnt6 += __popcll(__ballot(d == 6));
            cnt7 += __popcll(__ballot(d == 7));
            unsigned long long mask = __ballot((unsigned)d < (unsigned)SB);
            while (mask) {
                int i = __ffsll(mask) - 1;
                mask &= mask - 1;
                int b = __shfl(d, i, 64);        // uniform
                int nv = n0 + u * 64 + i;
                lacc[wid][b][lane] += xg[(size_t)nv * DQ + lane];
            }
        }
    }
    if (lane == 0) {
        lcnt[wid][0] = cnt0; lcnt[wid][1] = cnt1; lcnt[wid][2] = cnt2; lcnt[wid][3] = cnt3;
        lcnt[wid][4] = cnt4; lcnt[wid][5] = cnt5; lcnt[wid][6] = cnt6; lcnt[wid][7] = cnt7;
    }
    __syncthreads();

    int b = threadIdx.x >> 6;           // 0..7
    int l = threadIdx.x & 63;
    float a = 0.f;
#pragma unroll
    for (int w = 0; w < SW; ++w) a += lacc[w][b][l];
    int gk = g * KQ + kbase + b;
    float nea = DECAYF * embed_avg[(size_t)gk * dq + l] + (1.0f - DECAYF) * a;
    out_avg[(size_t)gk * dq + l] = nea;
    if (l == 0) {
        int c = 0;
#pragma unroll
        for (int w = 0; w < SW; ++w) c += lcnt[w][b];
        out_cs[gk] = DECAYF * cs[gk] + (1.0f - DECAYF) * (float)c;
    }
}

// ---- tot[g] ----
__global__ void k_tot(const float* __restrict__ out_cs, float* __restrict__ tot) {
    int g = blockIdx.x;
    __shared__ float red[256];
    float s = 0.f;
    for (int k = threadIdx.x; k < KQ; k += 256) s += out_cs[g * KQ + k];
    red[threadIdx.x] = s;
    __syncthreads();
    for (int off = 128; off > 0; off >>= 1) {
        if (threadIdx.x < off) red[threadIdx.x] += red[threadIdx.x + off];
        __syncthreads();
    }
    if (threadIdx.x == 0) tot[g] = red[0];
}

// ---- new_embed ----
__global__ void k_embed(const float* __restrict__ out_avg, const float* __restrict__ out_cs,
                        const float* __restrict__ tot, float* __restrict__ out_embed) {
    int t = blockIdx.x * 256 + threadIdx.x;
    int gk = t >> 6;
    int g = gk >> 10;
    double ncs = (double)out_cs[gk];
    double tt = (double)tot[g];
    double sm = (ncs + (double)EPSF) / (tt + (double)KQ * (double)EPSF) * tt;
    out_embed[t] = (float)((double)out_avg[t] / sm);
}

extern "C" void kernel_launch(void* const* d_in, const int* in_sizes, int n_in,
                              void* d_out, int out_size, void* d_ws, size_t ws_size,
                              hipStream_t stream) {
    const float* x         = (const float*)d_in[0];
    const float* embed     = (const float*)d_in[1];
    const float* embed_avg = (const float*)d_in[2];
    const float* cs        = (const float*)d_in[3];
    float* out = (float*)d_out;
    float* zq        = out + OFF_ZQ;
    float* ind_out   = out + OFF_IND;
    float* out_embed = out + OFF_EMB;
    float* out_cs    = out + OFF_CS;
    float* out_avg   = out + OFF_AVG;

    char* ws = (char*)d_ws;
    int*    ind_t = (int*)(ws + WS_IND);
    float*  e2    = (float*)(ws + WS_E2);
    ushort* eh    = (ushort*)(ws + WS_EH);
    ushort* el    = (ushort*)(ws + WS_EL);
    float*  tot   = (float*)(ws + WS_TOT);
    int*    ctr   = (int*)(ws + WS_CTR);
    int2*   list  = (int2*)(ws + WS_LIST);

    hipMemsetAsync(ctr, 0, sizeof(int), stream);
    k_prep<<<GQ * KQ / 256, 256, 0, stream>>>(embed, e2, eh, el);
    dim3 g1(NQ / MBLK, GQ);
    k_scores_mfma<<<g1, 256, 0, stream>>>(x, eh, el, e2, ind_t, ctr, list);
    k_recheck<<<256, 256, 0, stream>>>(x, embed, ctr, list, ind_t);
    k_gather<<<(NQ * GQ * 16) / 256, 256, 0, stream>>>(embed, ind_t, zq, ind_out);
    k_segsum2<<<512, 512, 0, stream>>>(x, ind_t, embed_avg, cs, out_cs, out_avg);
    k_tot<<<GQ, 256, 0, stream>>>(out_cs, tot);
    k_embed<<<(GQ * KQ * dq) / 256, 256, 0, stream>>>(out_avg, out_cs, tot, out_embed);
}

// Round 7
// 214.944 us; speedup vs baseline: 1.3060x; 1.1885x over previous
//
#include <hip/hip_runtime.h>
#include <cstdint>

// Problem constants
#define GQ 4
#define KQ 1024
#define DQ 256     // = GQ * dq
#define dq 64
#define NQ 32768   // B*S = 8*4096
#define DECAYF 0.99f
#define EPSF 1e-5f

// Output flat offsets (floats)
#define OFF_ZQ    0
#define OFF_IND   8388608
#define OFF_EMB   8519680
#define OFF_CS    8781824
#define OFF_AVG   8785920

// Workspace layout (bytes)
#define WS_IND   0              // int32 [GQ][NQ]  (transposed ind)
#define WS_E2    524288         // float [GQ][KQ]
#define WS_EH    540672         // ushort(bf16) fragment-ordered embed hi
#define WS_EL    1064960        // ushort(bf16) fragment-ordered embed lo
#define WS_TOT   1589248        // float [GQ]
#define WS_CTR   1589264        // int
#define WS_LIST  1589280        // int2 [CAP]
#define CAP      16384

#define MARGIN 0.02f

#define MBLK 128   // rows per block (4 waves x 32 rows)

typedef __attribute__((ext_vector_type(8))) short bf16x8;
typedef __attribute__((ext_vector_type(4))) float f32x4;

// f32 -> bf16 hi/lo split of 8 values, scaled by 2 (exact exponent shift):
// hi = truncate, lo = RNE(residual)
__device__ __forceinline__ void split8_2x(float4 u, float4 v, bf16x8& h, bf16x8& l) {
    float f[8] = {u.x, u.y, u.z, u.w, v.x, v.y, v.z, v.w};
#pragma unroll
    for (int j = 0; j < 8; ++j) {
        float s = f[j] * 2.0f;
        uint32_t b = __float_as_uint(s);
        uint32_t hb = b & 0xffff0000u;
        float r = s - __uint_as_float(hb);
        uint32_t rb = __float_as_uint(r);
        h[j] = (short)(hb >> 16);
        l[j] = (short)((rb + 0x7fffu + ((rb >> 16) & 1u)) >> 16);
    }
}

// ---- prep: e2[g][k]; embed split into bf16 hi/lo in FRAGMENT ORDER ----
// layout (elements): g*65536 + ((ch*2 + c)*4 + l4)*512 + co*8 + jj
//   where k = ch*64+co, j = c*32 + l4*8 + jj
__global__ void k_prep(const float* __restrict__ embed, float* __restrict__ e2,
                       ushort* __restrict__ eh, ushort* __restrict__ el) {
    int t = blockIdx.x * blockDim.x + threadIdx.x; // 0..GQ*KQ-1
    int g = t >> 10, k = t & 1023;
    int ch = k >> 6, co = k & 63;
    const float* row = embed + (size_t)t * dq;
    float s = 0.f;
#pragma unroll
    for (int c = 0; c < 2; ++c)
#pragma unroll
        for (int l4 = 0; l4 < 4; ++l4) {
            bf16x8 h, l;
            size_t addr = (size_t)g * 65536 + (size_t)((ch * 2 + c) * 4 + l4) * 512 + co * 8;
#pragma unroll
            for (int jj = 0; jj < 8; ++jj) {
                float f = row[c * 32 + l4 * 8 + jj];
                s = fmaf(f, f, s);
                uint32_t b = __float_as_uint(f);
                uint32_t hb = (b + 0x7fffu + ((b >> 16) & 1u)) & 0xffff0000u;
                float r = f - __uint_as_float(hb);
                uint32_t rb = __float_as_uint(r);
                h[jj] = (short)(hb >> 16);
                l[jj] = (short)((rb + 0x7fffu + ((rb >> 16) & 1u)) >> 16);
            }
            *reinterpret_cast<bf16x8*>(eh + addr) = h;
            *reinterpret_cast<bf16x8*>(el + addr) = l;
        }
    e2[t] = s;
}

// ---- MFMA scores + fused top-2 argmax ----
// 4 waves; each wave owns 32 rows (m=2 tiles) x all 1024 cols (16 chunks of 64).
// B loads: fragment-ordered, 4x256B contiguous segments per instruction.
// acc init = -e2[col]; x pre-scaled by 2 => s = acc directly after the K loop.
// No block barriers; no cross-wave merge (each wave owns whole rows).
__launch_bounds__(256)
__global__ void k_scores_mfma(const float* __restrict__ x,
                              const ushort* __restrict__ eh,
                              const ushort* __restrict__ el,
                              const float* __restrict__ e2,
                              int* __restrict__ ind_t,
                              int* __restrict__ ctr, int2* __restrict__ list) {
    int g = blockIdx.y;
    int n0 = blockIdx.x * MBLK;
    int wid = threadIdx.x >> 6;
    int lane = threadIdx.x & 63;
    int l15 = lane & 15, l4 = lane >> 4;

    // A fragments: rows n0 + wid*32 + m*16 + l15, k = c*32 + l4*8 + j (x2 scale)
    bf16x8 ah[2][2], al[2][2];
#pragma unroll
    for (int m = 0; m < 2; ++m)
#pragma unroll
        for (int c = 0; c < 2; ++c) {
            const float4* p = reinterpret_cast<const float4*>(
                x + (size_t)(n0 + wid * 32 + m * 16 + l15) * DQ + g * dq + c * 32 + l4 * 8);
            split8_2x(p[0], p[1], ah[m][c], al[m][c]);
        }

    const ushort* ehg = eh + (size_t)g * 65536;
    const ushort* elg = el + (size_t)g * 65536;
    const float*  e2g = e2 + (size_t)g * KQ;

    float m1[2][4], m2[2][4];
    int   k1[2][4];
#pragma unroll
    for (int m = 0; m < 2; ++m)
#pragma unroll
        for (int r = 0; r < 4; ++r) { m1[m][r] = -3.4e38f; m2[m][r] = -3.4e38f; k1[m][r] = 0; }

#pragma unroll 1
    for (int ch = 0; ch < 16; ++ch) {
        int cb = ch * 64;
        float e2v[4];
#pragma unroll
        for (int n = 0; n < 4; ++n) e2v[n] = e2g[cb + n * 16 + l15];

        f32x4 acc[2][4];
#pragma unroll
        for (int m = 0; m < 2; ++m)
#pragma unroll
            for (int n = 0; n < 4; ++n)
                acc[m][n] = (f32x4){-e2v[n], -e2v[n], -e2v[n], -e2v[n]};

#pragma unroll
        for (int c = 0; c < 2; ++c) {
            bf16x8 bh[4], bl[4];
            size_t base = (size_t)((ch * 2 + c) * 4 + l4) * 512 + l15 * 8;
#pragma unroll
            for (int n = 0; n < 4; ++n) {
                bh[n] = *reinterpret_cast<const bf16x8*>(ehg + base + n * 128);
                bl[n] = *reinterpret_cast<const bf16x8*>(elg + base + n * 128);
            }
#pragma unroll
            for (int m = 0; m < 2; ++m)
#pragma unroll
                for (int n = 0; n < 4; ++n) {
                    acc[m][n] = __builtin_amdgcn_mfma_f32_16x16x32_bf16(ah[m][c], bh[n], acc[m][n], 0, 0, 0);
                    acc[m][n] = __builtin_amdgcn_mfma_f32_16x16x32_bf16(ah[m][c], bl[n], acc[m][n], 0, 0, 0);
                    acc[m][n] = __builtin_amdgcn_mfma_f32_16x16x32_bf16(al[m][c], bh[n], acc[m][n], 0, 0, 0);
                }
        }
        // epilogue: s = acc (e2 and 2x already folded); top-2 per (m,r)
#pragma unroll
        for (int n = 0; n < 4; ++n) {
            int col = cb + n * 16 + l15;
#pragma unroll
            for (int m = 0; m < 2; ++m)
#pragma unroll
                for (int r = 0; r < 4; ++r) {
                    float s = acc[m][n][r];
                    bool gt = s > m1[m][r];
                    m2[m][r] = __builtin_amdgcn_fmed3f(s, m1[m][r], m2[m][r]);
                    k1[m][r] = gt ? col : k1[m][r];
                    m1[m][r] = fmaxf(m1[m][r], s);
                }
        }
    }

    // cross-lane reduce over the 16 col-lanes; rows live in (l4, m, r)
#pragma unroll
    for (int m = 0; m < 2; ++m)
#pragma unroll
        for (int r = 0; r < 4; ++r) {
            float a1 = m1[m][r], a2 = m2[m][r];
            int ak = k1[m][r];
#pragma unroll
            for (int d = 1; d < 16; d <<= 1) {
                float o1 = __shfl_xor(a1, d, 64);
                float o2 = __shfl_xor(a2, d, 64);
                int   ok = __shfl_xor(ak, d, 64);
                bool sw = (o1 > a1) || (o1 == a1 && ok < ak);
                float big = sw ? o1 : a1;
                int bigk = sw ? ok : ak;
                float small = sw ? a1 : o1;
                a2 = fmaxf(fmaxf(a2, o2), small);
                a1 = big; ak = bigk;
            }
            if (l15 == 0) {
                int row = n0 + wid * 32 + m * 16 + l4 * 4 + r;
                ind_t[(size_t)g * NQ + row] = ak;
                if (a1 - a2 < MARGIN) {
                    int idx = atomicAdd(ctr, 1);
                    if (idx < CAP) list[idx] = make_int2(row, g);
                }
            }
        }
}

// ---- f64 recheck of flagged queries ----
__launch_bounds__(256)
__global__ void k_recheck(const float* __restrict__ x, const float* __restrict__ embed,
                          const int* __restrict__ ctr, const int2* __restrict__ list,
                          int* __restrict__ ind_t) {
    __shared__ double sv[256];
    __shared__ int si[256];
    int nitems = *ctr;
    if (nitems > CAP) nitems = CAP;
    for (int it = blockIdx.x; it < nitems; it += gridDim.x) {
        int2 q = list[it];
        int n = q.x, g = q.y;
        const float* xrow = x + (size_t)n * DQ + g * dq;
        double best = -1e300;
        int bk = KQ;
        for (int k = threadIdx.x; k < KQ; k += 256) {
            const float* er = embed + ((size_t)g * KQ + k) * dq;
            double dot = 0.0, ee = 0.0;
#pragma unroll 8
            for (int j = 0; j < dq; ++j) {
                double ev = (double)er[j];
                dot = fma((double)xrow[j], ev, dot);
                ee = fma(ev, ev, ee);
            }
            double s = 2.0 * dot - ee;
            if (s > best || (s == best && k < bk)) { best = s; bk = k; }
        }
        sv[threadIdx.x] = best; si[threadIdx.x] = bk;
        __syncthreads();
        for (int off = 128; off > 0; off >>= 1) {
            if (threadIdx.x < off) {
                double ov = sv[threadIdx.x + off]; int oi = si[threadIdx.x + off];
                if (ov > sv[threadIdx.x] || (ov == sv[threadIdx.x] && oi < si[threadIdx.x])) {
                    sv[threadIdx.x] = ov; si[threadIdx.x] = oi;
                }
            }
            __syncthreads();
        }
        if (threadIdx.x == 0) ind_t[(size_t)g * NQ + n] = si[0];
        __syncthreads();
    }
}

// ---- zq gather + ind output ----
__global__ void k_gather(const float* __restrict__ embed, const int* __restrict__ ind_t,
                         float* __restrict__ zq, float* __restrict__ ind_out) {
    int t = blockIdx.x * 256 + threadIdx.x;   // float4 index
    int j4 = t & 15;
    int g = (t >> 4) & 3;
    int n = t >> 6;
    int k = ind_t[(size_t)g * NQ + n];
    const float4* e4 = reinterpret_cast<const float4*>(embed) + ((size_t)(g * KQ + k) * 16 + j4);
    reinterpret_cast<float4*>(zq)[t] = *e4;
    if (t < NQ * GQ) {
        int n2 = t >> 2, g2 = t & 3;
        ind_out[t] = (float)ind_t[(size_t)g2 * NQ + n2];
    }
}

// ---- segment sum v2: 8 bins/block, 8 waves split the N-scan, LDS accumulate ----
#define SB 8   // bins per block
#define SW 8   // waves per block
__launch_bounds__(512)
__global__ void k_segsum2(const float* __restrict__ x, const int* __restrict__ ind_t,
                          const float* __restrict__ embed_avg, const float* __restrict__ cs,
                          float* __restrict__ out_cs, float* __restrict__ out_avg) {
    __shared__ float lacc[SW][SB][64];
    __shared__ int   lcnt[SW][SB];

    int g = blockIdx.x >> 7;            // 512 blocks: 4 g * 128
    int kbase = (blockIdx.x & 127) * SB;
    int wid = threadIdx.x >> 6;
    int lane = threadIdx.x & 63;

    for (int i = threadIdx.x; i < SW * SB * 64; i += 512) ((float*)lacc)[i] = 0.f;
    if (threadIdx.x < SW * SB) ((int*)lcnt)[threadIdx.x] = 0;
    __syncthreads();

    const int* ip = ind_t + (size_t)g * NQ;
    const float* xg = x + g * dq;
    int cnt0 = 0, cnt1 = 0, cnt2 = 0, cnt3 = 0, cnt4 = 0, cnt5 = 0, cnt6 = 0, cnt7 = 0;
    int wbase = wid * (NQ / SW);

    for (int n0 = wbase; n0 < wbase + NQ / SW; n0 += 256) {
        int v0 = ip[n0 + lane];
        int v1 = ip[n0 + 64 + lane];
        int v2 = ip[n0 + 128 + lane];
        int v3 = ip[n0 + 192 + lane];
#pragma unroll
        for (int u = 0; u < 4; ++u) {
            int v = u == 0 ? v0 : (u == 1 ? v1 : (u == 2 ? v2 : v3));
            int d = v - kbase;
            cnt0 += __popcll(__ballot(d == 0));
            cnt1 += __popcll(__ballot(d == 1));
            cnt2 += __popcll(__ballot(d == 2));
            cnt3 += __popcll(__ballot(d == 3));
            cnt4 += __popcll(__ballot(d == 4));
            cnt5 += __popcll(__ballot(d == 5));
            cnt6 += __popcll(__ballot(d == 6));
            cnt7 += __popcll(__ballot(d == 7));
            unsigned long long mask = __ballot((unsigned)d < (unsigned)SB);
            while (mask) {
                int i = __ffsll(mask) - 1;
                mask &= mask - 1;
                int b = __shfl(d, i, 64);        // uniform
                int nv = n0 + u * 64 + i;
                lacc[wid][b][lane] += xg[(size_t)nv * DQ + lane];
            }
        }
    }
    if (lane == 0) {
        lcnt[wid][0] = cnt0; lcnt[wid][1] = cnt1; lcnt[wid][2] = cnt2; lcnt[wid][3] = cnt3;
        lcnt[wid][4] = cnt4; lcnt[wid][5] = cnt5; lcnt[wid][6] = cnt6; lcnt[wid][7] = cnt7;
    }
    __syncthreads();

    int b = threadIdx.x >> 6;           // 0..7
    int l = threadIdx.x & 63;
    float a = 0.f;
#pragma unroll
    for (int w = 0; w < SW; ++w) a += lacc[w][b][l];
    int gk = g * KQ + kbase + b;
    float nea = DECAYF * embed_avg[(size_t)gk * dq + l] + (1.0f - DECAYF) * a;
    out_avg[(size_t)gk * dq + l] = nea;
    if (l == 0) {
        int c = 0;
#pragma unroll
        for (int w = 0; w < SW; ++w) c += lcnt[w][b];
        out_cs[gk] = DECAYF * cs[gk] + (1.0f - DECAYF) * (float)c;
    }
}

// ---- tot[g] ----
__global__ void k_tot(const float* __restrict__ out_cs, float* __restrict__ tot) {
    int g = blockIdx.x;
    __shared__ float red[256];
    float s = 0.f;
    for (int k = threadIdx.x; k < KQ; k += 256) s += out_cs[g * KQ + k];
    red[threadIdx.x] = s;
    __syncthreads();
    for (int off = 128; off > 0; off >>= 1) {
        if (threadIdx.x < off) red[threadIdx.x] += red[threadIdx.x + off];
        __syncthreads();
    }
    if (threadIdx.x == 0) tot[g] = red[0];
}

// ---- new_embed ----
__global__ void k_embed(const float* __restrict__ out_avg, const float* __restrict__ out_cs,
                        const float* __restrict__ tot, float* __restrict__ out_embed) {
    int t = blockIdx.x * 256 + threadIdx.x;
    int gk = t >> 6;
    int g = gk >> 10;
    double ncs = (double)out_cs[gk];
    double tt = (double)tot[g];
    double sm = (ncs + (double)EPSF) / (tt + (double)KQ * (double)EPSF) * tt;
    out_embed[t] = (float)((double)out_avg[t] / sm);
}

extern "C" void kernel_launch(void* const* d_in, const int* in_sizes, int n_in,
                              void* d_out, int out_size, void* d_ws, size_t ws_size,
                              hipStream_t stream) {
    const float* x         = (const float*)d_in[0];
    const float* embed     = (const float*)d_in[1];
    const float* embed_avg = (const float*)d_in[2];
    const float* cs        = (const float*)d_in[3];
    float* out = (float*)d_out;
    float* zq        = out + OFF_ZQ;
    float* ind_out   = out + OFF_IND;
    float* out_embed = out + OFF_EMB;
    float* out_cs    = out + OFF_CS;
    float* out_avg   = out + OFF_AVG;

    char* ws = (char*)d_ws;
    int*    ind_t = (int*)(ws + WS_IND);
    float*  e2    = (float*)(ws + WS_E2);
    ushort* eh    = (ushort*)(ws + WS_EH);
    ushort* el    = (ushort*)(ws + WS_EL);
    float*  tot   = (float*)(ws + WS_TOT);
    int*    ctr   = (int*)(ws + WS_CTR);
    int2*   list  = (int2*)(ws + WS_LIST);

    hipMemsetAsync(ctr, 0, sizeof(int), stream);
    k_prep<<<GQ * KQ / 256, 256, 0, stream>>>(embed, e2, eh, el);
    dim3 g1(NQ / MBLK, GQ);
    k_scores_mfma<<<g1, 256, 0, stream>>>(x, eh, el, e2, ind_t, ctr, list);
    k_recheck<<<256, 256, 0, stream>>>(x, embed, ctr, list, ind_t);
    k_gather<<<(NQ * GQ * 16) / 256, 256, 0, stream>>>(embed, ind_t, zq, ind_out);
    k_segsum2<<<512, 512, 0, stream>>>(x, ind_t, embed_avg, cs, out_cs, out_avg);
    k_tot<<<GQ, 256, 0, stream>>>(out_cs, tot);
    k_embed<<<(GQ * KQ * dq) / 256, 256, 0, stream>>>(out_avg, out_cs, tot, out_embed);
}

// Round 8
// 184.050 us; speedup vs baseline: 1.5252x; 1.1679x over previous
//
#include <hip/hip_runtime.h>
#include <cstdint>

// Problem constants
#define GQ 4
#define KQ 1024
#define DQ 256     // = GQ * dq
#define dq 64
#define NQ 32768   // B*S = 8*4096
#define DECAYF 0.99f
#define EPSF 1e-5f

// Output flat offsets (floats)
#define OFF_ZQ    0
#define OFF_IND   8388608
#define OFF_EMB   8519680
#define OFF_CS    8781824
#define OFF_AVG   8785920

// Workspace layout (bytes)
#define WS_IND   0              // int32 [GQ][NQ]  (transposed ind)
#define WS_E2    524288         // float [GQ][KQ]
#define WS_EH    540672         // ushort(bf16) fragment-ordered embed hi
#define WS_EL    1064960        // ushort(bf16) fragment-ordered embed lo
#define WS_TOT   1589248        // float [GQ]
#define WS_CTR   1589264        // int
#define WS_LIST  1589280        // int2 [CAP]
#define CAP      16384

#define MARGIN 0.02f

#define MBLK 256   // rows per block (4 waves x 64 rows)

typedef __attribute__((ext_vector_type(8))) short bf16x8;
typedef __attribute__((ext_vector_type(4))) float f32x4;

// f32 -> bf16 hi/lo split of 8 values, scaled by 2 (exact exponent shift):
// hi = truncate, lo = RNE(residual)
__device__ __forceinline__ void split8_2x(float4 u, float4 v, bf16x8& h, bf16x8& l) {
    float f[8] = {u.x, u.y, u.z, u.w, v.x, v.y, v.z, v.w};
#pragma unroll
    for (int j = 0; j < 8; ++j) {
        float s = f[j] * 2.0f;
        uint32_t b = __float_as_uint(s);
        uint32_t hb = b & 0xffff0000u;
        float r = s - __uint_as_float(hb);
        uint32_t rb = __float_as_uint(r);
        h[j] = (short)(hb >> 16);
        l[j] = (short)((rb + 0x7fffu + ((rb >> 16) & 1u)) >> 16);
    }
}

// ---- prep (coalesced): e2[g][k]; embed split into bf16 hi/lo, FRAGMENT ORDER ----
// thread t = (row, frag): row = t>>3 (0..4095), f = t&7, c = f>>2, l4 = f&3
// layout (elements): g*65536 + ((ch*2 + c)*4 + l4)*512 + co*8 + jj,  k=ch*64+co
__global__ void k_prep(const float* __restrict__ embed, float* __restrict__ e2,
                       ushort* __restrict__ eh, ushort* __restrict__ el) {
    int t = blockIdx.x * 256 + threadIdx.x;   // 0..32767
    int row = t >> 3;                         // g*1024 + k
    int f = t & 7;
    int c = f >> 2, l4 = f & 3;
    int g = row >> 10, k = row & 1023;
    int ch = k >> 6, co = k & 63;

    const float4* p = reinterpret_cast<const float4*>(embed + (size_t)row * dq + f * 8);
    float4 u = p[0], v = p[1];
    float fv[8] = {u.x, u.y, u.z, u.w, v.x, v.y, v.z, v.w};
    bf16x8 h, l;
    float s = 0.f;
#pragma unroll
    for (int jj = 0; jj < 8; ++jj) {
        float x = fv[jj];
        s = fmaf(x, x, s);
        uint32_t b = __float_as_uint(x);
        uint32_t hb = (b + 0x7fffu + ((b >> 16) & 1u)) & 0xffff0000u;
        float r = x - __uint_as_float(hb);
        uint32_t rb = __float_as_uint(r);
        h[jj] = (short)(hb >> 16);
        l[jj] = (short)((rb + 0x7fffu + ((rb >> 16) & 1u)) >> 16);
    }
    size_t addr = (size_t)g * 65536 + (size_t)((ch * 2 + c) * 4 + l4) * 512 + co * 8;
    *reinterpret_cast<bf16x8*>(eh + addr) = h;
    *reinterpret_cast<bf16x8*>(el + addr) = l;
    // e2: reduce across the 8 lanes sharing this row (lanes row*8..row*8+7)
    s += __shfl_xor(s, 1, 64);
    s += __shfl_xor(s, 2, 64);
    s += __shfl_xor(s, 4, 64);
    if (f == 0) e2[row] = s;
}

// ---- MFMA scores + fused top-2 argmax + fused zq/ind writes ----
// 4 waves; each wave owns 64 rows (m=4 tiles) x all 1024 cols (16 chunks).
__launch_bounds__(256)
__global__ void k_scores_mfma(const float* __restrict__ x,
                              const ushort* __restrict__ eh,
                              const ushort* __restrict__ el,
                              const float* __restrict__ e2,
                              const float* __restrict__ embed,
                              int* __restrict__ ind_t,
                              float* __restrict__ zq,
                              float* __restrict__ ind_out,
                              int* __restrict__ ctr, int2* __restrict__ list) {
    int g = blockIdx.y;
    int n0 = blockIdx.x * MBLK;
    int wid = threadIdx.x >> 6;
    int lane = threadIdx.x & 63;
    int l15 = lane & 15, l4 = lane >> 4;

    __shared__ int ckk[4][64];

    // A fragments: rows n0 + wid*64 + m*16 + l15, j = c*32 + l4*8 + jj (x2 scale)
    bf16x8 ah[4][2], al[4][2];
#pragma unroll
    for (int m = 0; m < 4; ++m)
#pragma unroll
        for (int c = 0; c < 2; ++c) {
            const float4* p = reinterpret_cast<const float4*>(
                x + (size_t)(n0 + wid * 64 + m * 16 + l15) * DQ + g * dq + c * 32 + l4 * 8);
            split8_2x(p[0], p[1], ah[m][c], al[m][c]);
        }

    const ushort* ehg = eh + (size_t)g * 65536;
    const ushort* elg = el + (size_t)g * 65536;
    const float*  e2g = e2 + (size_t)g * KQ;

    float m1[4][4], m2[4][4];
    int   k1[4][4];
#pragma unroll
    for (int m = 0; m < 4; ++m)
#pragma unroll
        for (int r = 0; r < 4; ++r) { m1[m][r] = -3.4e38f; m2[m][r] = -3.4e38f; k1[m][r] = 0; }

    float e2cur[4];
#pragma unroll
    for (int n = 0; n < 4; ++n) e2cur[n] = e2g[n * 16 + l15];

#pragma unroll 1
    for (int ch = 0; ch < 16; ++ch) {
        int cb = ch * 64;
        // B loads for the whole chunk (both halves), pinned above MFMAs
        bf16x8 bh0[4], bl0[4], bh1[4], bl1[4];
        {
            size_t base0 = (size_t)((ch * 2 + 0) * 4 + l4) * 512 + l15 * 8;
            size_t base1 = (size_t)((ch * 2 + 1) * 4 + l4) * 512 + l15 * 8;
#pragma unroll
            for (int n = 0; n < 4; ++n) {
                bh0[n] = *reinterpret_cast<const bf16x8*>(ehg + base0 + n * 128);
                bl0[n] = *reinterpret_cast<const bf16x8*>(elg + base0 + n * 128);
                bh1[n] = *reinterpret_cast<const bf16x8*>(ehg + base1 + n * 128);
                bl1[n] = *reinterpret_cast<const bf16x8*>(elg + base1 + n * 128);
            }
        }
        // prefetch next chunk's e2
        float e2nxt[4];
        if (ch < 15) {
#pragma unroll
            for (int n = 0; n < 4; ++n) e2nxt[n] = e2g[cb + 64 + n * 16 + l15];
        }
        __builtin_amdgcn_sched_barrier(0);

        f32x4 acc[4][4];
#pragma unroll
        for (int m = 0; m < 4; ++m)
#pragma unroll
            for (int n = 0; n < 4; ++n)
                acc[m][n] = (f32x4){-e2cur[n], -e2cur[n], -e2cur[n], -e2cur[n]};

#pragma unroll
        for (int m = 0; m < 4; ++m)
#pragma unroll
            for (int n = 0; n < 4; ++n) {
                acc[m][n] = __builtin_amdgcn_mfma_f32_16x16x32_bf16(ah[m][0], bh0[n], acc[m][n], 0, 0, 0);
                acc[m][n] = __builtin_amdgcn_mfma_f32_16x16x32_bf16(ah[m][0], bl0[n], acc[m][n], 0, 0, 0);
                acc[m][n] = __builtin_amdgcn_mfma_f32_16x16x32_bf16(al[m][0], bh0[n], acc[m][n], 0, 0, 0);
            }
#pragma unroll
        for (int m = 0; m < 4; ++m)
#pragma unroll
            for (int n = 0; n < 4; ++n) {
                acc[m][n] = __builtin_amdgcn_mfma_f32_16x16x32_bf16(ah[m][1], bh1[n], acc[m][n], 0, 0, 0);
                acc[m][n] = __builtin_amdgcn_mfma_f32_16x16x32_bf16(ah[m][1], bl1[n], acc[m][n], 0, 0, 0);
                acc[m][n] = __builtin_amdgcn_mfma_f32_16x16x32_bf16(al[m][1], bh1[n], acc[m][n], 0, 0, 0);
            }

        // epilogue: s = acc; top-2 per (m,r)
#pragma unroll
        for (int n = 0; n < 4; ++n) {
            int col = cb + n * 16 + l15;
#pragma unroll
            for (int m = 0; m < 4; ++m)
#pragma unroll
                for (int r = 0; r < 4; ++r) {
                    float s = acc[m][n][r];
                    bool gt = s > m1[m][r];
                    m2[m][r] = __builtin_amdgcn_fmed3f(s, m1[m][r], m2[m][r]);
                    k1[m][r] = gt ? col : k1[m][r];
                    m1[m][r] = fmaxf(m1[m][r], s);
                }
        }
#pragma unroll
        for (int n = 0; n < 4; ++n) e2cur[n] = e2nxt[n];
    }

    // cross-lane reduce over the 16 col-lanes; rows live in (m, l4, r)
#pragma unroll
    for (int m = 0; m < 4; ++m)
#pragma unroll
        for (int r = 0; r < 4; ++r) {
            float a1 = m1[m][r], a2 = m2[m][r];
            int ak = k1[m][r];
#pragma unroll
            for (int d = 1; d < 16; d <<= 1) {
                float o1 = __shfl_xor(a1, d, 64);
                float o2 = __shfl_xor(a2, d, 64);
                int   ok = __shfl_xor(ak, d, 64);
                bool sw = (o1 > a1) || (o1 == a1 && ok < ak);
                float big = sw ? o1 : a1;
                int bigk = sw ? ok : ak;
                float small = sw ? a1 : o1;
                a2 = fmaxf(fmaxf(a2, o2), small);
                a1 = big; ak = bigk;
            }
            if (l15 == 0) {
                int rloc = m * 16 + l4 * 4 + r;            // 0..63 within wave
                int row = n0 + wid * 64 + rloc;
                ckk[wid][rloc] = ak;
                ind_t[(size_t)g * NQ + row] = ak;
                if (a1 - a2 < MARGIN) {
                    int idx = atomicAdd(ctr, 1);
                    if (idx < CAP) list[idx] = make_int2(row, g);
                }
            }
        }
    __syncthreads();

    // fused zq gather: each wave writes its own 64 rows (lane = dim)
#pragma unroll 4
    for (int rr = 0; rr < 64; ++rr) {
        int k = ckk[wid][rr];
        float v = embed[((size_t)(g * KQ + k)) * dq + lane];
        zq[(size_t)(n0 + wid * 64 + rr) * DQ + g * dq + lane] = v;
    }
    // ind output (one row per lane)
    ind_out[(size_t)(n0 + wid * 64 + lane) * GQ + g] = (float)ckk[wid][lane];
}

// ---- f64 recheck of flagged queries (also patches zq / ind_out) ----
__launch_bounds__(256)
__global__ void k_recheck(const float* __restrict__ x, const float* __restrict__ embed,
                          const int* __restrict__ ctr, const int2* __restrict__ list,
                          int* __restrict__ ind_t, float* __restrict__ zq,
                          float* __restrict__ ind_out) {
    __shared__ double sv[256];
    __shared__ int si[256];
    int nitems = *ctr;
    if (nitems > CAP) nitems = CAP;
    for (int it = blockIdx.x; it < nitems; it += gridDim.x) {
        int2 q = list[it];
        int n = q.x, g = q.y;
        const float* xrow = x + (size_t)n * DQ + g * dq;
        double best = -1e300;
        int bk = KQ;
        for (int k = threadIdx.x; k < KQ; k += 256) {
            const float* er = embed + ((size_t)g * KQ + k) * dq;
            double dot = 0.0, ee = 0.0;
#pragma unroll 8
            for (int j = 0; j < dq; ++j) {
                double ev = (double)er[j];
                dot = fma((double)xrow[j], ev, dot);
                ee = fma(ev, ev, ee);
            }
            double s = 2.0 * dot - ee;
            if (s > best || (s == best && k < bk)) { best = s; bk = k; }
        }
        sv[threadIdx.x] = best; si[threadIdx.x] = bk;
        __syncthreads();
        for (int off = 128; off > 0; off >>= 1) {
            if (threadIdx.x < off) {
                double ov = sv[threadIdx.x + off]; int oi = si[threadIdx.x + off];
                if (ov > sv[threadIdx.x] || (ov == sv[threadIdx.x] && oi < si[threadIdx.x])) {
                    sv[threadIdx.x] = ov; si[threadIdx.x] = oi;
                }
            }
            __syncthreads();
        }
        int kbest = si[0];
        if (threadIdx.x == 0) {
            ind_t[(size_t)g * NQ + n] = kbest;
            ind_out[(size_t)n * GQ + g] = (float)kbest;
        }
        if (threadIdx.x < dq)
            zq[(size_t)n * DQ + g * dq + threadIdx.x] =
                embed[((size_t)g * KQ + kbest) * dq + threadIdx.x];
        __syncthreads();
    }
}

// ---- segment sum: 8 bins/block, 8 waves split the N-scan, LDS accumulate ----
#define SB 8   // bins per block
#define SW 8   // waves per block
__launch_bounds__(512)
__global__ void k_segsum2(const float* __restrict__ x, const int* __restrict__ ind_t,
                          const float* __restrict__ embed_avg, const float* __restrict__ cs,
                          float* __restrict__ out_cs, float* __restrict__ out_avg) {
    __shared__ float lacc[SW][SB][64];
    __shared__ int   lcnt[SW][SB];

    int g = blockIdx.x >> 7;            // 512 blocks: 4 g * 128
    int kbase = (blockIdx.x & 127) * SB;
    int wid = threadIdx.x >> 6;
    int lane = threadIdx.x & 63;

    for (int i = threadIdx.x; i < SW * SB * 64; i += 512) ((float*)lacc)[i] = 0.f;
    if (threadIdx.x < SW * SB) ((int*)lcnt)[threadIdx.x] = 0;
    __syncthreads();

    const int* ip = ind_t + (size_t)g * NQ;
    const float* xg = x + g * dq;
    int cnt0 = 0, cnt1 = 0, cnt2 = 0, cnt3 = 0, cnt4 = 0, cnt5 = 0, cnt6 = 0, cnt7 = 0;
    int wbase = wid * (NQ / SW);

    for (int n0 = wbase; n0 < wbase + NQ / SW; n0 += 256) {
        int v0 = ip[n0 + lane];
        int v1 = ip[n0 + 64 + lane];
        int v2 = ip[n0 + 128 + lane];
        int v3 = ip[n0 + 192 + lane];
#pragma unroll
        for (int u = 0; u < 4; ++u) {
            int v = u == 0 ? v0 : (u == 1 ? v1 : (u == 2 ? v2 : v3));
            int d = v - kbase;
            cnt0 += __popcll(__ballot(d == 0));
            cnt1 += __popcll(__ballot(d == 1));
            cnt2 += __popcll(__ballot(d == 2));
            cnt3 += __popcll(__ballot(d == 3));
            cnt4 += __popcll(__ballot(d == 4));
            cnt5 += __popcll(__ballot(d == 5));
            cnt6 += __popcll(__ballot(d == 6));
            cnt7 += __popcll(__ballot(d == 7));
            unsigned long long mask = __ballot((unsigned)d < (unsigned)SB);
            while (mask) {
                int i = __ffsll(mask) - 1;
                mask &= mask - 1;
                int b = __shfl(d, i, 64);        // uniform
                int nv = n0 + u * 64 + i;
                lacc[wid][b][lane] += xg[(size_t)nv * DQ + lane];
            }
        }
    }
    if (lane == 0) {
        lcnt[wid][0] = cnt0; lcnt[wid][1] = cnt1; lcnt[wid][2] = cnt2; lcnt[wid][3] = cnt3;
        lcnt[wid][4] = cnt4; lcnt[wid][5] = cnt5; lcnt[wid][6] = cnt6; lcnt[wid][7] = cnt7;
    }
    __syncthreads();

    int b = threadIdx.x >> 6;           // 0..7
    int l = threadIdx.x & 63;
    float a = 0.f;
#pragma unroll
    for (int w = 0; w < SW; ++w) a += lacc[w][b][l];
    int gk = g * KQ + kbase + b;
    float nea = DECAYF * embed_avg[(size_t)gk * dq + l] + (1.0f - DECAYF) * a;
    out_avg[(size_t)gk * dq + l] = nea;
    if (l == 0) {
        int c = 0;
#pragma unroll
        for (int w = 0; w < SW; ++w) c += lcnt[w][b];
        out_cs[gk] = DECAYF * cs[gk] + (1.0f - DECAYF) * (float)c;
    }
}

// ---- new_embed (tot computed inline per block) ----
__global__ void k_embed(const float* __restrict__ out_avg, const float* __restrict__ out_cs,
                        float* __restrict__ out_embed) {
    __shared__ float red[256];
    int t = blockIdx.x * 256 + threadIdx.x;   // element index; block spans 4 gk, same g
    int g = (t >> 6) >> 10;
    // inline tot[g]: reduce out_cs[g][0..1023]
    float s = 0.f;
    const float4* csp = reinterpret_cast<const float4*>(out_cs + g * KQ);
    {
        float4 v = csp[threadIdx.x];
        s = (v.x + v.y) + (v.z + v.w);
    }
    red[threadIdx.x] = s;
    __syncthreads();
    for (int off = 128; off > 0; off >>= 1) {
        if (threadIdx.x < off) red[threadIdx.x] += red[threadIdx.x + off];
        __syncthreads();
    }
    double tt = (double)red[0];
    int gk = t >> 6;
    double ncs = (double)out_cs[gk];
    double sm = (ncs + (double)EPSF) / (tt + (double)KQ * (double)EPSF) * tt;
    out_embed[t] = (float)((double)out_avg[t] / sm);
}

extern "C" void kernel_launch(void* const* d_in, const int* in_sizes, int n_in,
                              void* d_out, int out_size, void* d_ws, size_t ws_size,
                              hipStream_t stream) {
    const float* x         = (const float*)d_in[0];
    const float* embed     = (const float*)d_in[1];
    const float* embed_avg = (const float*)d_in[2];
    const float* cs        = (const float*)d_in[3];
    float* out = (float*)d_out;
    float* zq        = out + OFF_ZQ;
    float* ind_out   = out + OFF_IND;
    float* out_embed = out + OFF_EMB;
    float* out_cs    = out + OFF_CS;
    float* out_avg   = out + OFF_AVG;

    char* ws = (char*)d_ws;
    int*    ind_t = (int*)(ws + WS_IND);
    float*  e2    = (float*)(ws + WS_E2);
    ushort* eh    = (ushort*)(ws + WS_EH);
    ushort* el    = (ushort*)(ws + WS_EL);
    int*    ctr   = (int*)(ws + WS_CTR);
    int2*   list  = (int2*)(ws + WS_LIST);

    hipMemsetAsync(ctr, 0, sizeof(int), stream);
    k_prep<<<128, 256, 0, stream>>>(embed, e2, eh, el);
    dim3 g1(NQ / MBLK, GQ);
    k_scores_mfma<<<g1, 256, 0, stream>>>(x, eh, el, e2, embed, ind_t, zq, ind_out, ctr, list);
    k_recheck<<<256, 256, 0, stream>>>(x, embed, ctr, list, ind_t, zq, ind_out);
    k_segsum2<<<512, 512, 0, stream>>>(x, ind_t, embed_avg, cs, out_cs, out_avg);
    k_embed<<<(GQ * KQ * dq) / 256, 256, 0, stream>>>(out_avg, out_cs, out_embed);
}

// Round 9
// 162.293 us; speedup vs baseline: 1.7296x; 1.1341x over previous
//
#include <hip/hip_runtime.h>
#include <cstdint>

// Problem constants
#define GQ 4
#define KQ 1024
#define DQ 256     // = GQ * dq
#define dq 64
#define NQ 32768   // B*S = 8*4096
#define DECAYF 0.99f
#define EPSF 1e-5f

// Output flat offsets (floats)
#define OFF_ZQ    0
#define OFF_IND   8388608
#define OFF_EMB   8519680
#define OFF_CS    8781824
#define OFF_AVG   8785920

// Workspace layout (bytes)
#define WS_IND   0              // int32 [GQ][NQ]  (transposed ind)
#define WS_E2    524288         // float [GQ][KQ]
#define WS_EH    540672         // ushort(bf16) fragment-ordered embed hi
#define WS_EL    1064960        // ushort(bf16) fragment-ordered embed lo
#define WS_CTR   1589264        // int
#define WS_LIST  1589280        // int2 [CAP]
#define CAP      16384
#define WS_E2D   1720352        // double [GQ*KQ]  (f64 e^2 for recheck)

#define MARGIN 0.01f

#define MBLK 128   // rows per block (4 waves x 32 rows)

typedef __attribute__((ext_vector_type(8))) short bf16x8;
typedef __attribute__((ext_vector_type(4))) float f32x4;

// f32 -> bf16 hi/lo split of 8 values, scaled by 2 (exact exponent shift):
// hi = truncate, lo = RNE(residual)
__device__ __forceinline__ void split8_2x(float4 u, float4 v, bf16x8& h, bf16x8& l) {
    float f[8] = {u.x, u.y, u.z, u.w, v.x, v.y, v.z, v.w};
#pragma unroll
    for (int j = 0; j < 8; ++j) {
        float s = f[j] * 2.0f;
        uint32_t b = __float_as_uint(s);
        uint32_t hb = b & 0xffff0000u;
        float r = s - __uint_as_float(hb);
        uint32_t rb = __float_as_uint(r);
        h[j] = (short)(hb >> 16);
        l[j] = (short)((rb + 0x7fffu + ((rb >> 16) & 1u)) >> 16);
    }
}

// ---- prep (coalesced): e2 (f32+f64); embed split into bf16 hi/lo, FRAGMENT ORDER ----
// thread t = (row, frag): row = t>>3 (0..4095), f = t&7, c = f>>2, l4 = f&3
// layout (elements): g*65536 + ch*4096 + (c*4 + l4)*512 + co*8 + jj,  k=ch*64+co
__global__ void k_prep(const float* __restrict__ embed, float* __restrict__ e2,
                       double* __restrict__ e2d,
                       ushort* __restrict__ eh, ushort* __restrict__ el) {
    int t = blockIdx.x * 256 + threadIdx.x;   // 0..32767
    int row = t >> 3;                         // g*1024 + k
    int f = t & 7;
    int c = f >> 2, l4 = f & 3;
    int g = row >> 10, k = row & 1023;
    int ch = k >> 6, co = k & 63;

    const float4* p = reinterpret_cast<const float4*>(embed + (size_t)row * dq + f * 8);
    float4 u = p[0], v = p[1];
    float fv[8] = {u.x, u.y, u.z, u.w, v.x, v.y, v.z, v.w};
    bf16x8 h, l;
    double s = 0.0;
#pragma unroll
    for (int jj = 0; jj < 8; ++jj) {
        float x = fv[jj];
        s = fma((double)x, (double)x, s);
        uint32_t b = __float_as_uint(x);
        uint32_t hb = (b + 0x7fffu + ((b >> 16) & 1u)) & 0xffff0000u;
        float r = x - __uint_as_float(hb);
        uint32_t rb = __float_as_uint(r);
        h[jj] = (short)(hb >> 16);
        l[jj] = (short)((rb + 0x7fffu + ((rb >> 16) & 1u)) >> 16);
    }
    size_t addr = (size_t)g * 65536 + (size_t)ch * 4096 + (size_t)(c * 4 + l4) * 512 + co * 8;
    *reinterpret_cast<bf16x8*>(eh + addr) = h;
    *reinterpret_cast<bf16x8*>(el + addr) = l;
    // reduce across the 8 lanes sharing this row
    s += __shfl_xor(s, 1, 64);
    s += __shfl_xor(s, 2, 64);
    s += __shfl_xor(s, 4, 64);
    if (f == 0) { e2[row] = (float)s; e2d[row] = s; }
}

// ---- MFMA scores: LDS double-buffered B staging + fused argmax + zq/ind ----
// 4 waves; each wave owns 32 rows (m=2 tiles) x all 1024 cols (16 chunks).
// Per chunk 16 KB (eh 8K + el 8K) staged ONCE per block via global_load_lds.
__launch_bounds__(256)
__global__ void k_scores_mfma(const float* __restrict__ x,
                              const ushort* __restrict__ eh,
                              const ushort* __restrict__ el,
                              const float* __restrict__ e2,
                              const float* __restrict__ embed,
                              int* __restrict__ ind_t,
                              float* __restrict__ zq,
                              float* __restrict__ ind_out,
                              int* __restrict__ ctr, int2* __restrict__ list) {
    int g = blockIdx.y;
    int n0 = blockIdx.x * MBLK;
    int tid = threadIdx.x;
    int wid = tid >> 6;
    int lane = tid & 63;
    int l15 = lane & 15, l4 = lane >> 4;

    __shared__ ushort lds[2][8192];   // [buf][eh 4096 | el 4096] = 16 KB per buf
    __shared__ int ckk[4][32];

    // A fragments: rows n0 + wid*32 + m*16 + l15, j = c*32 + l4*8 + jj (x2 scale)
    bf16x8 ah[2][2], al[2][2];
#pragma unroll
    for (int m = 0; m < 2; ++m)
#pragma unroll
        for (int c = 0; c < 2; ++c) {
            const float4* p = reinterpret_cast<const float4*>(
                x + (size_t)(n0 + wid * 32 + m * 16 + l15) * DQ + g * dq + c * 32 + l4 * 8);
            split8_2x(p[0], p[1], ah[m][c], al[m][c]);
        }

    const ushort* ehg = eh + (size_t)g * 65536;
    const ushort* elg = el + (size_t)g * 65536;
    const float*  e2g = e2 + (size_t)g * KQ;

    float m1[2][4], m2[2][4];
    int   k1[2][4];
#pragma unroll
    for (int m = 0; m < 2; ++m)
#pragma unroll
        for (int r = 0; r < 4; ++r) { m1[m][r] = -3.4e38f; m2[m][r] = -3.4e38f; k1[m][r] = 0; }

    // stage(b, ch): 16 KB, linear by tid (wave-uniform base + lane*16)
    int wu = (tid & ~63) * 8;   // wave-uniform ushort offset (= wid*512)
#define STAGE(b, ch)                                                               \
    do {                                                                           \
        const ushort* s0_ = ehg + (ch) * 4096 + tid * 8;                           \
        const ushort* s1_ = elg + (ch) * 4096 + tid * 8;                           \
        __builtin_amdgcn_global_load_lds(s0_,        &lds[b][wu],        16, 0, 0);\
        __builtin_amdgcn_global_load_lds(s0_ + 2048, &lds[b][2048 + wu], 16, 0, 0);\
        __builtin_amdgcn_global_load_lds(s1_,        &lds[b][4096 + wu], 16, 0, 0);\
        __builtin_amdgcn_global_load_lds(s1_ + 2048, &lds[b][6144 + wu], 16, 0, 0);\
    } while (0)

    float e2cur[4];
#pragma unroll
    for (int n = 0; n < 4; ++n) e2cur[n] = e2g[n * 16 + l15];

    STAGE(0, 0);
    int cur = 0;

#pragma unroll 1
    for (int ch = 0; ch < 16; ++ch) {
        int cb = ch * 64;
        __syncthreads();                    // drains vmcnt -> lds[cur] ready
        if (ch < 15) STAGE(cur ^ 1, ch + 1);

        float e2nxt[4];
        if (ch < 15) {
#pragma unroll
            for (int n = 0; n < 4; ++n) e2nxt[n] = e2g[cb + 64 + n * 16 + l15];
        }

        f32x4 acc[2][4];
#pragma unroll
        for (int m = 0; m < 2; ++m)
#pragma unroll
            for (int n = 0; n < 4; ++n)
                acc[m][n] = (f32x4){-e2cur[n], -e2cur[n], -e2cur[n], -e2cur[n]};

#pragma unroll
        for (int c = 0; c < 2; ++c) {
            bf16x8 bh[4], bl[4];
            int base = (c * 4 + l4) * 512 + l15 * 8;
#pragma unroll
            for (int n = 0; n < 4; ++n) {
                bh[n] = *reinterpret_cast<const bf16x8*>(&lds[cur][base + n * 128]);
                bl[n] = *reinterpret_cast<const bf16x8*>(&lds[cur][4096 + base + n * 128]);
            }
#pragma unroll
            for (int m = 0; m < 2; ++m)
#pragma unroll
                for (int n = 0; n < 4; ++n) {
                    acc[m][n] = __builtin_amdgcn_mfma_f32_16x16x32_bf16(ah[m][c], bh[n], acc[m][n], 0, 0, 0);
                    acc[m][n] = __builtin_amdgcn_mfma_f32_16x16x32_bf16(ah[m][c], bl[n], acc[m][n], 0, 0, 0);
                    acc[m][n] = __builtin_amdgcn_mfma_f32_16x16x32_bf16(al[m][c], bh[n], acc[m][n], 0, 0, 0);
                }
        }

        // epilogue: s = acc (e2, 2x folded); top-2 per (m,r)
#pragma unroll
        for (int n = 0; n < 4; ++n) {
            int col = cb + n * 16 + l15;
#pragma unroll
            for (int m = 0; m < 2; ++m)
#pragma unroll
                for (int r = 0; r < 4; ++r) {
                    float s = acc[m][n][r];
                    bool gt = s > m1[m][r];
                    m2[m][r] = __builtin_amdgcn_fmed3f(s, m1[m][r], m2[m][r]);
                    k1[m][r] = gt ? col : k1[m][r];
                    m1[m][r] = fmaxf(m1[m][r], s);
                }
        }
#pragma unroll
        for (int n = 0; n < 4; ++n) e2cur[n] = e2nxt[n];
        cur ^= 1;
    }
#undef STAGE

    // cross-lane reduce over the 16 col-lanes; rows live in (m, l4, r)
#pragma unroll
    for (int m = 0; m < 2; ++m)
#pragma unroll
        for (int r = 0; r < 4; ++r) {
            float a1 = m1[m][r], a2 = m2[m][r];
            int ak = k1[m][r];
#pragma unroll
            for (int d = 1; d < 16; d <<= 1) {
                float o1 = __shfl_xor(a1, d, 64);
                float o2 = __shfl_xor(a2, d, 64);
                int   ok = __shfl_xor(ak, d, 64);
                bool sw = (o1 > a1) || (o1 == a1 && ok < ak);
                float big = sw ? o1 : a1;
                int bigk = sw ? ok : ak;
                float small = sw ? a1 : o1;
                a2 = fmaxf(fmaxf(a2, o2), small);
                a1 = big; ak = bigk;
            }
            if (l15 == 0) {
                int rloc = m * 16 + l4 * 4 + r;            // 0..31 within wave
                int row = n0 + wid * 32 + rloc;
                ckk[wid][rloc] = ak;
                ind_t[(size_t)g * NQ + row] = ak;
                if (a1 - a2 < MARGIN) {
                    int idx = atomicAdd(ctr, 1);
                    if (idx < CAP) list[idx] = make_int2(row, g);
                }
            }
        }
    __syncthreads();

    // fused zq gather: each wave writes its own 32 rows (lane = dim)
#pragma unroll 4
    for (int rr = 0; rr < 32; ++rr) {
        int k = ckk[wid][rr];
        float v = embed[((size_t)(g * KQ + k)) * dq + lane];
        zq[(size_t)(n0 + wid * 32 + rr) * DQ + g * dq + lane] = v;
    }
    // ind output
    if (lane < 32)
        ind_out[(size_t)(n0 + wid * 32 + lane) * GQ + g] = (float)ckk[wid][lane];
}

// ---- f64 recheck of flagged queries (uses precomputed f64 e2; patches outputs) ----
__launch_bounds__(256)
__global__ void k_recheck(const float* __restrict__ x, const float* __restrict__ embed,
                          const double* __restrict__ e2d,
                          const int* __restrict__ ctr, const int2* __restrict__ list,
                          int* __restrict__ ind_t, float* __restrict__ zq,
                          float* __restrict__ ind_out) {
    __shared__ double sv[256];
    __shared__ int si[256];
    int nitems = *ctr;
    if (nitems > CAP) nitems = CAP;
    for (int it = blockIdx.x; it < nitems; it += gridDim.x) {
        int2 q = list[it];
        int n = q.x, g = q.y;
        const float* xrow = x + (size_t)n * DQ + g * dq;
        double best = -1e300;
        int bk = KQ;
        for (int k = threadIdx.x; k < KQ; k += 256) {
            const float* er = embed + ((size_t)g * KQ + k) * dq;
            double dot = 0.0;
#pragma unroll 8
            for (int j = 0; j < dq; ++j)
                dot = fma((double)xrow[j], (double)er[j], dot);
            double s = 2.0 * dot - e2d[g * KQ + k];
            if (s > best || (s == best && k < bk)) { best = s; bk = k; }
        }
        sv[threadIdx.x] = best; si[threadIdx.x] = bk;
        __syncthreads();
        for (int off = 128; off > 0; off >>= 1) {
            if (threadIdx.x < off) {
                double ov = sv[threadIdx.x + off]; int oi = si[threadIdx.x + off];
                if (ov > sv[threadIdx.x] || (ov == sv[threadIdx.x] && oi < si[threadIdx.x])) {
                    sv[threadIdx.x] = ov; si[threadIdx.x] = oi;
                }
            }
            __syncthreads();
        }
        int kbest = si[0];
        if (threadIdx.x == 0) {
            ind_t[(size_t)g * NQ + n] = kbest;
            ind_out[(size_t)n * GQ + g] = (float)kbest;
        }
        if (threadIdx.x < dq)
            zq[(size_t)n * DQ + g * dq + threadIdx.x] =
                embed[((size_t)g * KQ + kbest) * dq + threadIdx.x];
        __syncthreads();
    }
}

// ---- segment sum: 8 bins/block, 8 waves split the N-scan, LDS accumulate ----
#define SB 8   // bins per block
#define SW 8   // waves per block
__launch_bounds__(512)
__global__ void k_segsum2(const float* __restrict__ x, const int* __restrict__ ind_t,
                          const float* __restrict__ embed_avg, const float* __restrict__ cs,
                          float* __restrict__ out_cs, float* __restrict__ out_avg) {
    __shared__ float lacc[SW][SB][64];
    __shared__ int   lcnt[SW][SB];

    int g = blockIdx.x >> 7;            // 512 blocks: 4 g * 128
    int kbase = (blockIdx.x & 127) * SB;
    int wid = threadIdx.x >> 6;
    int lane = threadIdx.x & 63;

    for (int i = threadIdx.x; i < SW * SB * 64; i += 512) ((float*)lacc)[i] = 0.f;
    if (threadIdx.x < SW * SB) ((int*)lcnt)[threadIdx.x] = 0;
    __syncthreads();

    const int* ip = ind_t + (size_t)g * NQ;
    const float* xg = x + g * dq;
    int cnt0 = 0, cnt1 = 0, cnt2 = 0, cnt3 = 0, cnt4 = 0, cnt5 = 0, cnt6 = 0, cnt7 = 0;
    int wbase = wid * (NQ / SW);

    for (int n0 = wbase; n0 < wbase + NQ / SW; n0 += 256) {
        int v0 = ip[n0 + lane];
        int v1 = ip[n0 + 64 + lane];
        int v2 = ip[n0 + 128 + lane];
        int v3 = ip[n0 + 192 + lane];
#pragma unroll
        for (int u = 0; u < 4; ++u) {
            int v = u == 0 ? v0 : (u == 1 ? v1 : (u == 2 ? v2 : v3));
            int d = v - kbase;
            cnt0 += __popcll(__ballot(d == 0));
            cnt1 += __popcll(__ballot(d == 1));
            cnt2 += __popcll(__ballot(d == 2));
            cnt3 += __popcll(__ballot(d == 3));
            cnt4 += __popcll(__ballot(d == 4));
            cnt5 += __popcll(__ballot(d == 5));
            cnt6 += __popcll(__ballot(d == 6));
            cnt7 += __popcll(__ballot(d == 7));
            unsigned long long mask = __ballot((unsigned)d < (unsigned)SB);
            while (mask) {
                int i = __ffsll(mask) - 1;
                mask &= mask - 1;
                int b = __shfl(d, i, 64);        // uniform
                int nv = n0 + u * 64 + i;
                lacc[wid][b][lane] += xg[(size_t)nv * DQ + lane];
            }
        }
    }
    if (lane == 0) {
        lcnt[wid][0] = cnt0; lcnt[wid][1] = cnt1; lcnt[wid][2] = cnt2; lcnt[wid][3] = cnt3;
        lcnt[wid][4] = cnt4; lcnt[wid][5] = cnt5; lcnt[wid][6] = cnt6; lcnt[wid][7] = cnt7;
    }
    __syncthreads();

    int b = threadIdx.x >> 6;           // 0..7
    int l = threadIdx.x & 63;
    float a = 0.f;
#pragma unroll
    for (int w = 0; w < SW; ++w) a += lacc[w][b][l];
    int gk = g * KQ + kbase + b;
    float nea = DECAYF * embed_avg[(size_t)gk * dq + l] + (1.0f - DECAYF) * a;
    out_avg[(size_t)gk * dq + l] = nea;
    if (l == 0) {
        int c = 0;
#pragma unroll
        for (int w = 0; w < SW; ++w) c += lcnt[w][b];
        out_cs[gk] = DECAYF * cs[gk] + (1.0f - DECAYF) * (float)c;
    }
}

// ---- new_embed (tot computed inline per block) ----
__global__ void k_embed(const float* __restrict__ out_avg, const float* __restrict__ out_cs,
                        float* __restrict__ out_embed) {
    __shared__ float red[256];
    int t = blockIdx.x * 256 + threadIdx.x;   // element index; block spans 4 gk, same g
    int g = (t >> 6) >> 10;
    float s = 0.f;
    const float4* csp = reinterpret_cast<const float4*>(out_cs + g * KQ);
    {
        float4 v = csp[threadIdx.x];
        s = (v.x + v.y) + (v.z + v.w);
    }
    red[threadIdx.x] = s;
    __syncthreads();
    for (int off = 128; off > 0; off >>= 1) {
        if (threadIdx.x < off) red[threadIdx.x] += red[threadIdx.x + off];
        __syncthreads();
    }
    double tt = (double)red[0];
    int gk = t >> 6;
    double ncs = (double)out_cs[gk];
    double sm = (ncs + (double)EPSF) / (tt + (double)KQ * (double)EPSF) * tt;
    out_embed[t] = (float)((double)out_avg[t] / sm);
}

extern "C" void kernel_launch(void* const* d_in, const int* in_sizes, int n_in,
                              void* d_out, int out_size, void* d_ws, size_t ws_size,
                              hipStream_t stream) {
    const float* x         = (const float*)d_in[0];
    const float* embed     = (const float*)d_in[1];
    const float* embed_avg = (const float*)d_in[2];
    const float* cs        = (const float*)d_in[3];
    float* out = (float*)d_out;
    float* zq        = out + OFF_ZQ;
    float* ind_out   = out + OFF_IND;
    float* out_embed = out + OFF_EMB;
    float* out_cs    = out + OFF_CS;
    float* out_avg   = out + OFF_AVG;

    char* ws = (char*)d_ws;
    int*    ind_t = (int*)(ws + WS_IND);
    float*  e2    = (float*)(ws + WS_E2);
    ushort* eh    = (ushort*)(ws + WS_EH);
    ushort* el    = (ushort*)(ws + WS_EL);
    int*    ctr   = (int*)(ws + WS_CTR);
    int2*   list  = (int2*)(ws + WS_LIST);
    double* e2d   = (double*)(ws + WS_E2D);

    hipMemsetAsync(ctr, 0, sizeof(int), stream);
    k_prep<<<128, 256, 0, stream>>>(embed, e2, e2d, eh, el);
    dim3 g1(NQ / MBLK, GQ);
    k_scores_mfma<<<g1, 256, 0, stream>>>(x, eh, el, e2, embed, ind_t, zq, ind_out, ctr, list);
    k_recheck<<<256, 256, 0, stream>>>(x, embed, e2d, ctr, list, ind_t, zq, ind_out);
    k_segsum2<<<512, 512, 0, stream>>>(x, ind_t, embed_avg, cs, out_cs, out_avg);
    k_embed<<<(GQ * KQ * dq) / 256, 256, 0, stream>>>(out_avg, out_cs, out_embed);
}